// Round 6
// baseline (512.834 us; speedup 1.0000x reference)
//
#include <hip/hip_runtime.h>

// SparseResBlock on MI355X — round 5: true spconv structure.
// Rulebook (pair lists, int-scan deterministic) built once; per conv:
//   Phase A: dense gather-GEMM over valid pairs -> pv[p][64] (bf16)
//   Phase B: per-output segmented sum of pv rows (no atomics) + fused stats
// Then BN finalize + (bnrelu | residual-final) passes.

constexpr int N_VOX = 200000;
constexpr int GEXT  = 128;
constexpr int C     = 64;
constexpr int K27   = 27;
constexpr int TBL_N = 2 * GEXT * GEXT * GEXT;  // 4,194,304
constexpr float EPSF = 1e-5f;

constexpr int NCH      = 391;               // ceil(N/512) chunks per offset
constexpr int CNT2N    = K27 * NCH;         // 10557
constexpr int PAIR_CAP = 460032;            // >> expected ~448k pairs, mult of 64
constexpr int TIL64    = PAIR_CAP / 64;     // 7188 64-pair blocks
constexpr int PBB      = 6250;              // phase-B blocks (32 outputs each)
constexpr int RBLK     = 128;               // stage-1 reduce blocks

using short8   = __attribute__((ext_vector_type(8))) short;
using floatx16 = __attribute__((ext_vector_type(16))) float;

static __device__ __forceinline__ ushort f2bf(float f) {
  union { float f; unsigned u; } a; a.f = f;
  unsigned r = a.u + 0x7fff + ((a.u >> 16) & 1);  // RTNE
  return (ushort)(r >> 16);
}
static __device__ __forceinline__ float bf2f(ushort h) {
  union { unsigned u; float f; } a; a.u = ((unsigned)h) << 16;
  return a.f;
}

// ---------------- rulebook build ----------------

__global__ __launch_bounds__(256) void k_fill(int* __restrict__ t,
                                              int* __restrict__ bsum,
                                              int* __restrict__ cnt2,
                                              int* __restrict__ inl) {
  int i = blockIdx.x * 256 + threadIdx.x;
  if (i < TBL_N) t[i] = -1;
  if (i < 4096) bsum[i] = 0;
  if (i < CNT2N) cnt2[i] = 0;
  if (i < PAIR_CAP) inl[i] = -1;
}

__global__ __launch_bounds__(256) void k_scatter(const int* __restrict__ coords,
                                                 int* __restrict__ t) {
  int n = blockIdx.x * 256 + threadIdx.x;
  if (n >= N_VOX) return;
  int4 c = reinterpret_cast<const int4*>(coords)[n];
  int lin = ((c.x * GEXT + c.y) * GEXT + c.z) * GEXT + c.w;
  t[lin] = n;
}

__global__ __launch_bounds__(256) void k_count(const int* __restrict__ coords,
                                               int* __restrict__ bsum) {
  int n = blockIdx.x * 256 + threadIdx.x;
  if (n >= N_VOX) return;
  int4 c = reinterpret_cast<const int4*>(coords)[n];
  int lin = ((c.x * GEXT + c.y) * GEXT + c.z) * GEXT + c.w;
  atomicAdd(&bsum[lin >> 10], 1);
}

__global__ __launch_bounds__(1024) void k_scan(const int* __restrict__ bsum,
                                               int* __restrict__ boff) {
  __shared__ int sc[1024];
  int t = threadIdx.x;
  int v0 = bsum[t * 4], v1 = bsum[t * 4 + 1], v2 = bsum[t * 4 + 2],
      v3 = bsum[t * 4 + 3];
  int s = v0 + v1 + v2 + v3;
  sc[t] = s;
  __syncthreads();
  for (int off = 1; off < 1024; off <<= 1) {
    int x = (t >= off) ? sc[t - off] : 0;
    __syncthreads();
    sc[t] += x;
    __syncthreads();
  }
  int excl = sc[t] - s;
  boff[t * 4]     = excl;
  boff[t * 4 + 1] = excl + v0;
  boff[t * 4 + 2] = excl + v0 + v1;
  boff[t * 4 + 3] = excl + v0 + v1 + v2;
}

__global__ __launch_bounds__(1024) void k_compact(int* __restrict__ table,
                                                  const int* __restrict__ boff,
                                                  int* __restrict__ perm) {
  __shared__ int wsum[16];
  int i = blockIdx.x * 1024 + threadIdx.x;
  int orig = table[i];
  bool valid = orig >= 0;
  unsigned long long bal = __ballot(valid);
  int lane = threadIdx.x & 63, wv = threadIdx.x >> 6;
  int before = __popcll(bal & ((1ull << lane) - 1ull));
  if (lane == 0) wsum[wv] = __popcll(bal);
  __syncthreads();
  int woff = 0;
  for (int w = 0; w < 16; ++w) woff += (w < wv) ? wsum[w] : 0;
  if (valid) {
    int j = boff[blockIdx.x] + woff + before;
    perm[j] = orig;
    table[i] = j;
  }
}

__global__ __launch_bounds__(256) void k_nbrp(const int* __restrict__ coords,
                                              const int* __restrict__ table,
                                              const int* __restrict__ perm,
                                              int* __restrict__ nbrp) {
  int j = blockIdx.x * 256 + threadIdx.x;
  if (j >= N_VOX) return;
  int orig = perm[j];
  int4 c = reinterpret_cast<const int4*>(coords)[orig];
  int k = 0;
  #pragma unroll
  for (int dx = -1; dx <= 1; ++dx)
    #pragma unroll
    for (int dy = -1; dy <= 1; ++dy)
      #pragma unroll
      for (int dz = -1; dz <= 1; ++dz) {
        int x = c.y + dx, y = c.z + dy, z = c.w + dz;
        int rank = -1;
        if (((unsigned)x < (unsigned)GEXT) & ((unsigned)y < (unsigned)GEXT) &
            ((unsigned)z < (unsigned)GEXT)) {
          int lin = ((c.x * GEXT + x) * GEXT + y) * GEXT + z;
          rank = table[lin];
        }
        nbrp[k * N_VOX + j] = rank;
        ++k;
      }
}

// pair counts per (offset, 512-output chunk)
__global__ __launch_bounds__(256) void k_cnt2(const int* __restrict__ nbrp,
                                              int* __restrict__ cnt2) {
  int gid = blockIdx.x * 256 + threadIdx.x;
  int k = gid / 200192, j = gid % 200192;  // 782 blocks of 256 per offset
  if (j >= N_VOX) return;
  if (nbrp[k * N_VOX + j] >= 0) atomicAdd(&cnt2[k * NCH + (j >> 9)], 1);
}

// per-offset totals
__global__ __launch_bounds__(512) void k_segtot(const int* __restrict__ cnt2,
                                                int* __restrict__ segs) {
  __shared__ int red[512];
  int k = blockIdx.x, t = threadIdx.x;
  red[t] = (t < NCH) ? cnt2[k * NCH + t] : 0;
  __syncthreads();
  for (int off = 256; off >= 1; off >>= 1) {
    if (t < off) red[t] += red[t + off];
    __syncthreads();
  }
  if (t == 0) segs[k] = red[0];
}

// serial 27-entry base computation (64-padded segments)
__global__ __launch_bounds__(64) void k_segbase(int* __restrict__ segs) {
  if (threadIdx.x == 0) {
    int b = 0;
    for (int k = 0; k < K27; ++k) {
      segs[32 + k] = b;
      b += (segs[k] + 63) & ~63;
    }
    segs[32 + K27] = b;  // total padded pair count
  }
}

// exclusive scan of chunk counts within each offset -> global pair offsets
__global__ __launch_bounds__(512) void k_choff(const int* __restrict__ cnt2,
                                               const int* __restrict__ segs,
                                               int* __restrict__ choff) {
  __shared__ int sc[512];
  int k = blockIdx.x, t = threadIdx.x;
  int v = (t < NCH) ? cnt2[k * NCH + t] : 0;
  sc[t] = v;
  __syncthreads();
  for (int off = 1; off < 512; off <<= 1) {
    int x = (t >= off) ? sc[t - off] : 0;
    __syncthreads();
    sc[t] += x;
    __syncthreads();
  }
  if (t < NCH) choff[k * NCH + t] = segs[32 + k] + sc[t] - v;
}

// emit pairs: in_list[p] = input rank; nbrp (in place) becomes pidx
__global__ __launch_bounds__(512) void k_pairs(int* __restrict__ nbrp,
                                               const int* __restrict__ choff,
                                               int* __restrict__ inl) {
  __shared__ int wsum[8];
  int k = blockIdx.x / NCH, c = blockIdx.x % NCH;
  int j = c * 512 + threadIdx.x;
  int v = (j < N_VOX) ? nbrp[k * N_VOX + j] : -1;
  bool valid = v >= 0;
  unsigned long long bal = __ballot(valid);
  int lane = threadIdx.x & 63, wv = threadIdx.x >> 6;
  int before = __popcll(bal & ((1ull << lane) - 1ull));
  if (lane == 0) wsum[wv] = __popcll(bal);
  __syncthreads();
  int woff = 0;
  #pragma unroll
  for (int w = 0; w < 8; ++w) woff += (w < wv) ? wsum[w] : 0;
  if (valid) {
    int p = choff[k * NCH + c] + woff + before;
    inl[p] = v;
    nbrp[k * N_VOX + j] = p;
  }
}

// 64-pair block -> offset id map
__global__ __launch_bounds__(256) void k_tilek(const int* __restrict__ segs,
                                               int* __restrict__ tile_k) {
  int t = blockIdx.x * 256 + threadIdx.x;
  if (t >= TIL64) return;
  int p0 = t * 64, kk = -1;
  if (p0 < segs[32 + K27]) {
    #pragma unroll 1
    for (int k = 0; k < K27; ++k)
      if (p0 >= segs[32 + k] && p0 < segs[32 + k + 1]) kk = k;
  }
  tile_k[t] = kk;
}

// ---------------- data prep ----------------

__global__ __launch_bounds__(256) void k_gcast(const float* __restrict__ feats,
                                               const int* __restrict__ perm,
                                               ushort* __restrict__ fbp) {
  int i = blockIdx.x * 256 + threadIdx.x;  // N*16 quads
  int j = i >> 4, seg = i & 15;
  int p = perm[j];
  float4 v = reinterpret_cast<const float4*>(feats)[(p << 4) + seg];
  ushort4 o;
  o.x = f2bf(v.x); o.y = f2bf(v.y); o.z = f2bf(v.z); o.w = f2bf(v.w);
  reinterpret_cast<ushort4*>(fbp)[i] = o;
}

// w[k][ci][co] f32 -> packed A-frags for mfma_32x32x16:
// [k][ch(2)][ks(4)][hi1(2)][row32][e8] bf16
__global__ __launch_bounds__(256) void k_castw(const float* __restrict__ w,
                                               ushort* __restrict__ wp) {
  int i = blockIdx.x * 256 + threadIdx.x;
  if (i >= K27 * 4096) return;
  int k = i >> 12, r = i & 4095, ci = r >> 6, co = r & 63;
  int ch = co >> 5, row = co & 31;
  int ks = ci >> 4, hi1 = (ci >> 3) & 1, e = ci & 7;
  int dst = ((((k * 2 + ch) * 4 + ks) * 2 + hi1) << 8) + row * 8 + e;
  wp[dst] = f2bf(w[i]);
}

// ---------------- conv phase A: pair GEMM -> pv ----------------
// block = 256 thr = 2 pair-subtiles x 2 cout-halves; 64 pairs, all same k.
__global__ __launch_bounds__(256, 4) void k_pva(
    const ushort* __restrict__ fin,   // [N][64] bf16 (rank space)
    const ushort* __restrict__ wp,    // packed weight frags
    const int* __restrict__ inl,      // [PAIR_CAP] input ranks (-1 pad)
    const int* __restrict__ tile_k,   // [TIL64]
    ushort* __restrict__ pv) {        // [PAIR_CAP][64]
  const int kk = tile_k[blockIdx.x];
  if (kk < 0) return;
  const int tid = threadIdx.x, lane = tid & 63, wv = tid >> 6;
  const int lo = lane & 31, hi = lane >> 5;
  const int ch = wv & 1, vh = wv >> 1;
  const int pr = blockIdx.x * 64 + vh * 32 + lo;
  const int idx = inl[pr];

  const char* wk = (const char*)wp + (kk << 13) + (ch << 12) + (lane << 4);
  short8 a0 = *(const short8*)(wk);
  short8 a1 = *(const short8*)(wk + 1024);
  short8 a2 = *(const short8*)(wk + 2048);
  short8 a3 = *(const short8*)(wk + 3072);

  short8 b0, b1, b2, b3;
  if (idx >= 0) {
    const char* b = (const char*)fin + ((size_t)idx << 7) + (hi << 4);
    b0 = *(const short8*)(b);
    b1 = *(const short8*)(b + 32);
    b2 = *(const short8*)(b + 64);
    b3 = *(const short8*)(b + 96);
  } else {
    b0 = short8{0,0,0,0,0,0,0,0}; b1 = b0; b2 = b0; b3 = b0;
  }

  floatx16 acc;
  #pragma unroll
  for (int j = 0; j < 16; ++j) acc[j] = 0.f;
  acc = __builtin_amdgcn_mfma_f32_32x32x16_bf16(a0, b0, acc, 0, 0, 0);
  acc = __builtin_amdgcn_mfma_f32_32x32x16_bf16(a1, b1, acc, 0, 0, 0);
  acc = __builtin_amdgcn_mfma_f32_32x32x16_bf16(a2, b2, acc, 0, 0, 0);
  acc = __builtin_amdgcn_mfma_f32_32x32x16_bf16(a3, b3, acc, 0, 0, 0);

  ushort* o = pv + ((size_t)pr << 6) + (ch << 5) + (hi << 2);
  #pragma unroll
  for (int rg = 0; rg < 4; ++rg) {
    ushort4 v;
    v.x = f2bf(acc[rg * 4 + 0]); v.y = f2bf(acc[rg * 4 + 1]);
    v.z = f2bf(acc[rg * 4 + 2]); v.w = f2bf(acc[rg * 4 + 3]);
    *(ushort4*)(o + (rg << 3)) = v;
  }
}

// ---------------- conv phase B: segmented sum + stats ----------------
// block = 256 thr = 32 outputs x 8 lanes (8 channels each).
template <bool OUT_F32>
__global__ __launch_bounds__(256) void k_pvb(
    const ushort* __restrict__ pv,    // [PAIR_CAP][64]
    const int* __restrict__ pidx,     // [27][N] pair ids (-1 invalid)
    const int* __restrict__ perm,     // rank -> orig (for f32 scatter)
    void* __restrict__ fout,
    float* __restrict__ part) {       // [PBB][128]
  __shared__ float sred[4][8][16];
  const int tid = threadIdx.x, lane = tid & 63, wv = tid >> 6;
  const int g = tid >> 3, e = tid & 7;
  const int j = blockIdx.x * 32 + g;

  int p[27];
  #pragma unroll
  for (int t = 0; t < K27; ++t) p[t] = pidx[t * N_VOX + j];

  float acc[8];
  #pragma unroll
  for (int r = 0; r < 8; ++r) acc[r] = 0.f;
  #pragma unroll
  for (int t = 0; t < K27; ++t) {
    if (p[t] >= 0) {
      short8 v = *(const short8*)(pv + ((size_t)p[t] << 6) + (e << 3));
      #pragma unroll
      for (int r = 0; r < 8; ++r) acc[r] += bf2f((ushort)v[r]);
    }
  }

  if (OUT_F32) {
    int pj = perm[j];
    float* o = (float*)fout + ((size_t)pj << 6) + (e << 3);
    float4 v0 = {acc[0], acc[1], acc[2], acc[3]};
    float4 v1 = {acc[4], acc[5], acc[6], acc[7]};
    *(float4*)o = v0;
    *(float4*)(o + 4) = v1;
  } else {
    ushort* o = (ushort*)fout + ((size_t)j << 6) + (e << 3);
    ushort4 v0, v1;
    v0.x = f2bf(acc[0]); v0.y = f2bf(acc[1]);
    v0.z = f2bf(acc[2]); v0.w = f2bf(acc[3]);
    v1.x = f2bf(acc[4]); v1.y = f2bf(acc[5]);
    v1.z = f2bf(acc[6]); v1.w = f2bf(acc[7]);
    *(ushort4*)o = v0;
    *(ushort4*)(o + 4) = v1;
  }

  // stats: reduce over the 8 groups within each wave (lanes stride-8), then LDS
  #pragma unroll
  for (int r = 0; r < 8; ++r) {
    float s = acc[r], ss = acc[r] * acc[r];
    s += __shfl_xor(s, 8);  ss += __shfl_xor(ss, 8);
    s += __shfl_xor(s, 16); ss += __shfl_xor(ss, 16);
    s += __shfl_xor(s, 32); ss += __shfl_xor(ss, 32);
    if (lane < 8) { sred[wv][lane][r] = s; sred[wv][lane][8 + r] = ss; }
  }
  __syncthreads();
  if (tid < 128) {
    int half = tid >> 6, ch = tid & 63;
    int e2 = ch >> 3, r2 = ch & 7;
    float v = sred[0][e2][half * 8 + r2] + sred[1][e2][half * 8 + r2] +
              sred[2][e2][half * 8 + r2] + sred[3][e2][half * 8 + r2];
    part[(size_t)blockIdx.x * 128 + tid] = v;
  }
}

// ---------------- BN / epilogue ----------------

__global__ __launch_bounds__(256) void k_red(const float* __restrict__ part,
                                             float* __restrict__ part2) {
  __shared__ float red[256];
  int tid = threadIdx.x;
  int e = tid & 127, g = tid >> 7;
  float s = 0.f;
  for (int r = blockIdx.x * 2 + g; r < PBB; r += 2 * RBLK)
    s += part[(size_t)r * 128 + e];
  red[tid] = s;
  __syncthreads();
  if (tid < 128) part2[(size_t)blockIdx.x * 128 + tid] = red[tid] + red[tid + 128];
}

__global__ __launch_bounds__(256) void k_bnfin(const float* __restrict__ part2,
                                               const float* __restrict__ gamma,
                                               const float* __restrict__ beta,
                                               float* __restrict__ ab) {
  __shared__ float fin[128];
  int tid = threadIdx.x;
  if (tid < 128) {
    float s = 0.f;
    for (int r = 0; r < RBLK; ++r) s += part2[(size_t)r * 128 + tid];
    fin[tid] = s;
  }
  __syncthreads();
  if (tid < 64) {
    float su = fin[tid], ss = fin[64 + tid];
    float mean = su / (float)N_VOX;
    float var  = ss / (float)N_VOX - mean * mean;
    float a = gamma[tid] * rsqrtf(var + EPSF);
    ab[tid]      = a;
    ab[64 + tid] = beta[tid] - mean * a;
  }
}

__global__ __launch_bounds__(256) void k_bnrelu8(ushort* __restrict__ x,
                                                 const float* __restrict__ ab) {
  int i = blockIdx.x * 256 + threadIdx.x;  // N*8 groups
  ushort4 v0 = reinterpret_cast<ushort4*>(x)[i * 2];
  ushort4 v1 = reinterpret_cast<ushort4*>(x)[i * 2 + 1];
  int cb = (i * 8) & 63;
  v0.x = f2bf(fmaxf(bf2f(v0.x) * ab[cb]     + ab[64 + cb],     0.f));
  v0.y = f2bf(fmaxf(bf2f(v0.y) * ab[cb + 1] + ab[64 + cb + 1], 0.f));
  v0.z = f2bf(fmaxf(bf2f(v0.z) * ab[cb + 2] + ab[64 + cb + 2], 0.f));
  v0.w = f2bf(fmaxf(bf2f(v0.w) * ab[cb + 3] + ab[64 + cb + 3], 0.f));
  v1.x = f2bf(fmaxf(bf2f(v1.x) * ab[cb + 4] + ab[64 + cb + 4], 0.f));
  v1.y = f2bf(fmaxf(bf2f(v1.y) * ab[cb + 5] + ab[64 + cb + 5], 0.f));
  v1.z = f2bf(fmaxf(bf2f(v1.z) * ab[cb + 6] + ab[64 + cb + 6], 0.f));
  v1.w = f2bf(fmaxf(bf2f(v1.w) * ab[cb + 7] + ab[64 + cb + 7], 0.f));
  reinterpret_cast<ushort4*>(x)[i * 2]     = v0;
  reinterpret_cast<ushort4*>(x)[i * 2 + 1] = v1;
}

__global__ __launch_bounds__(256) void k_final4(float* __restrict__ h2,
                                                const float* __restrict__ feats,
                                                const float* __restrict__ ab) {
  int i = blockIdx.x * 256 + threadIdx.x;
  float4 a = reinterpret_cast<float4*>(h2)[i];
  float4 f = reinterpret_cast<const float4*>(feats)[i];
  int cb = (i * 4) & 63;
  float4 o;
  o.x = fmaxf(a.x * ab[cb]     + ab[64 + cb]     + f.x, 0.f);
  o.y = fmaxf(a.y * ab[cb + 1] + ab[64 + cb + 1] + f.y, 0.f);
  o.z = fmaxf(a.z * ab[cb + 2] + ab[64 + cb + 2] + f.z, 0.f);
  o.w = fmaxf(a.w * ab[cb + 3] + ab[64 + cb + 3] + f.w, 0.f);
  reinterpret_cast<float4*>(h2)[i] = o;
}

extern "C" void kernel_launch(void* const* d_in, const int* in_sizes, int n_in,
                              void* d_out, int out_size, void* d_ws, size_t ws_size,
                              hipStream_t stream) {
  const float* feats  = (const float*)d_in[0];
  const float* w1     = (const float*)d_in[1];
  const float* g1     = (const float*)d_in[2];
  const float* b1     = (const float*)d_in[3];
  const float* w2     = (const float*)d_in[4];
  const float* g2     = (const float*)d_in[5];
  const float* b2     = (const float*)d_in[6];
  const int*   coords = (const int*)d_in[7];
  float* out = (float*)d_out;

  char* ws = (char*)d_ws;
  ushort* pv    = (ushort*)ws;  ws += (size_t)PAIR_CAP * C * 2;    // 58.9 MB
  int*    table = (int*)ws;     ws += (size_t)TBL_N * 4;           // 16.8 MB
  int*    nbrp  = (int*)ws;     ws += (size_t)K27 * N_VOX * 4;     // 21.6 MB
  ushort* fbp   = (ushort*)ws;  ws += (size_t)N_VOX * C * 2;       // 25.6 MB
  ushort* h1p   = (ushort*)ws;  ws += (size_t)N_VOX * C * 2;       // 25.6 MB
  int*    perm  = (int*)ws;     ws += (size_t)N_VOX * 4;
  ushort* wp1   = (ushort*)ws;  ws += (size_t)K27 * 4096 * 2;
  ushort* wp2   = (ushort*)ws;  ws += (size_t)K27 * 4096 * 2;
  int*    inl   = (int*)ws;     ws += (size_t)PAIR_CAP * 4;
  int*    bsum  = (int*)ws;     ws += 4096 * 4;
  int*    boff  = (int*)ws;     ws += 4096 * 4;
  int*    cnt2  = (int*)ws;     ws += 42240;
  int*    choff = (int*)ws;     ws += 42240;
  int*    segs  = (int*)ws;     ws += 256;
  int*    tilk  = (int*)ws;     ws += (size_t)TIL64 * 4;
  float*  part2 = (float*)ws;   ws += (size_t)RBLK * 128 * 4;
  float*  ab1   = (float*)ws;   ws += 512;
  float*  ab2   = (float*)ws;   ws += 512;
  float*  part  = (float*)table;  // alias: table dead after k_nbrp

  // rulebook
  k_fill<<<TBL_N / 256, 256, 0, stream>>>(table, bsum, cnt2, inl);
  k_scatter<<<(N_VOX + 255) / 256, 256, 0, stream>>>(coords, table);
  k_count<<<(N_VOX + 255) / 256, 256, 0, stream>>>(coords, bsum);
  k_scan<<<1, 1024, 0, stream>>>(bsum, boff);
  k_compact<<<TBL_N / 1024, 1024, 0, stream>>>(table, boff, perm);
  k_nbrp<<<(N_VOX + 255) / 256, 256, 0, stream>>>(coords, table, perm, nbrp);
  k_cnt2<<<K27 * 782, 256, 0, stream>>>(nbrp, cnt2);
  k_segtot<<<K27, 512, 0, stream>>>(cnt2, segs);
  k_segbase<<<1, 64, 0, stream>>>(segs);
  k_choff<<<K27, 512, 0, stream>>>(cnt2, segs, choff);
  k_pairs<<<K27 * NCH, 512, 0, stream>>>(nbrp, choff, inl);
  k_tilek<<<(TIL64 + 255) / 256, 256, 0, stream>>>(segs, tilk);

  // data prep
  k_gcast<<<N_VOX * 16 / 256, 256, 0, stream>>>(feats, perm, fbp);
  k_castw<<<(K27 * 4096 + 255) / 256, 256, 0, stream>>>(w1, wp1);
  k_castw<<<(K27 * 4096 + 255) / 256, 256, 0, stream>>>(w2, wp2);

  // conv1
  k_pva<<<TIL64, 256, 0, stream>>>(fbp, wp1, inl, tilk, pv);
  k_pvb<false><<<PBB, 256, 0, stream>>>(pv, nbrp, perm, h1p, part);
  k_red<<<RBLK, 256, 0, stream>>>(part, part2);
  k_bnfin<<<1, 256, 0, stream>>>(part2, g1, b1, ab1);
  k_bnrelu8<<<N_VOX * 8 / 256, 256, 0, stream>>>(h1p, ab1);

  // conv2
  k_pva<<<TIL64, 256, 0, stream>>>(h1p, wp2, inl, tilk, pv);
  k_pvb<true><<<PBB, 256, 0, stream>>>(pv, nbrp, perm, out, part);
  k_red<<<RBLK, 256, 0, stream>>>(part, part2);
  k_bnfin<<<1, 256, 0, stream>>>(part2, g2, b2, ab2);
  k_final4<<<N_VOX * 64 / 4 / 256, 256, 0, stream>>>(out, feats, ab2);
}

// Round 7
// 311.043 us; speedup vs baseline: 1.6488x; 1.6488x over previous
//
#include <hip/hip_runtime.h>

// SparseResBlock on MI355X — round 6: round-5 spconv structure with the
// atomic pair-count histogram replaced by ballot/popc block reduction
// (k_cnt2: 212us of atomic contention -> ~10us streaming).

constexpr int N_VOX = 200000;
constexpr int GEXT  = 128;
constexpr int C     = 64;
constexpr int K27   = 27;
constexpr int TBL_N = 2 * GEXT * GEXT * GEXT;  // 4,194,304
constexpr float EPSF = 1e-5f;

constexpr int NCH      = 391;               // ceil(N/512) chunks per offset
constexpr int PAIR_CAP = 460032;            // >> expected ~448k pairs, mult of 64
constexpr int TIL64    = PAIR_CAP / 64;     // 7188 64-pair blocks
constexpr int PBB      = 6250;              // phase-B blocks (32 outputs each)
constexpr int RBLK     = 128;               // stage-1 reduce blocks

using short8   = __attribute__((ext_vector_type(8))) short;
using floatx16 = __attribute__((ext_vector_type(16))) float;

static __device__ __forceinline__ ushort f2bf(float f) {
  union { float f; unsigned u; } a; a.f = f;
  unsigned r = a.u + 0x7fff + ((a.u >> 16) & 1);  // RTNE
  return (ushort)(r >> 16);
}
static __device__ __forceinline__ float bf2f(ushort h) {
  union { unsigned u; float f; } a; a.u = ((unsigned)h) << 16;
  return a.f;
}

// ---------------- rulebook build ----------------

__global__ __launch_bounds__(256) void k_fill(int* __restrict__ t,
                                              int* __restrict__ bsum,
                                              int* __restrict__ inl) {
  int i = blockIdx.x * 256 + threadIdx.x;
  if (i < TBL_N) t[i] = -1;
  if (i < 4096) bsum[i] = 0;
  if (i < PAIR_CAP) inl[i] = -1;
}

__global__ __launch_bounds__(256) void k_scatter(const int* __restrict__ coords,
                                                 int* __restrict__ t) {
  int n = blockIdx.x * 256 + threadIdx.x;
  if (n >= N_VOX) return;
  int4 c = reinterpret_cast<const int4*>(coords)[n];
  int lin = ((c.x * GEXT + c.y) * GEXT + c.z) * GEXT + c.w;
  t[lin] = n;
}

__global__ __launch_bounds__(256) void k_count(const int* __restrict__ coords,
                                               int* __restrict__ bsum) {
  int n = blockIdx.x * 256 + threadIdx.x;
  if (n >= N_VOX) return;
  int4 c = reinterpret_cast<const int4*>(coords)[n];
  int lin = ((c.x * GEXT + c.y) * GEXT + c.z) * GEXT + c.w;
  atomicAdd(&bsum[lin >> 10], 1);
}

__global__ __launch_bounds__(1024) void k_scan(const int* __restrict__ bsum,
                                               int* __restrict__ boff) {
  __shared__ int sc[1024];
  int t = threadIdx.x;
  int v0 = bsum[t * 4], v1 = bsum[t * 4 + 1], v2 = bsum[t * 4 + 2],
      v3 = bsum[t * 4 + 3];
  int s = v0 + v1 + v2 + v3;
  sc[t] = s;
  __syncthreads();
  for (int off = 1; off < 1024; off <<= 1) {
    int x = (t >= off) ? sc[t - off] : 0;
    __syncthreads();
    sc[t] += x;
    __syncthreads();
  }
  int excl = sc[t] - s;
  boff[t * 4]     = excl;
  boff[t * 4 + 1] = excl + v0;
  boff[t * 4 + 2] = excl + v0 + v1;
  boff[t * 4 + 3] = excl + v0 + v1 + v2;
}

__global__ __launch_bounds__(1024) void k_compact(int* __restrict__ table,
                                                  const int* __restrict__ boff,
                                                  int* __restrict__ perm) {
  __shared__ int wsum[16];
  int i = blockIdx.x * 1024 + threadIdx.x;
  int orig = table[i];
  bool valid = orig >= 0;
  unsigned long long bal = __ballot(valid);
  int lane = threadIdx.x & 63, wv = threadIdx.x >> 6;
  int before = __popcll(bal & ((1ull << lane) - 1ull));
  if (lane == 0) wsum[wv] = __popcll(bal);
  __syncthreads();
  int woff = 0;
  for (int w = 0; w < 16; ++w) woff += (w < wv) ? wsum[w] : 0;
  if (valid) {
    int j = boff[blockIdx.x] + woff + before;
    perm[j] = orig;
    table[i] = j;
  }
}

__global__ __launch_bounds__(256) void k_nbrp(const int* __restrict__ coords,
                                              const int* __restrict__ table,
                                              const int* __restrict__ perm,
                                              int* __restrict__ nbrp) {
  int j = blockIdx.x * 256 + threadIdx.x;
  if (j >= N_VOX) return;
  int orig = perm[j];
  int4 c = reinterpret_cast<const int4*>(coords)[orig];
  int k = 0;
  #pragma unroll
  for (int dx = -1; dx <= 1; ++dx)
    #pragma unroll
    for (int dy = -1; dy <= 1; ++dy)
      #pragma unroll
      for (int dz = -1; dz <= 1; ++dz) {
        int x = c.y + dx, y = c.z + dy, z = c.w + dz;
        int rank = -1;
        if (((unsigned)x < (unsigned)GEXT) & ((unsigned)y < (unsigned)GEXT) &
            ((unsigned)z < (unsigned)GEXT)) {
          int lin = ((c.x * GEXT + x) * GEXT + y) * GEXT + z;
          rank = table[lin];
        }
        nbrp[k * N_VOX + j] = rank;
        ++k;
      }
}

// pair counts per (offset, 512-output chunk): ballot/popc, no atomics
__global__ __launch_bounds__(512) void k_cnt2b(const int* __restrict__ nbrp,
                                               int* __restrict__ cnt2) {
  __shared__ int wsum[8];
  int k = blockIdx.x / NCH, c = blockIdx.x % NCH;
  int j = c * 512 + threadIdx.x;
  bool valid = (j < N_VOX) && (nbrp[k * N_VOX + j] >= 0);
  unsigned long long bal = __ballot(valid);
  int lane = threadIdx.x & 63, wv = threadIdx.x >> 6;
  if (lane == 0) wsum[wv] = __popcll(bal);
  __syncthreads();
  if (threadIdx.x == 0) {
    int s = 0;
    #pragma unroll
    for (int w = 0; w < 8; ++w) s += wsum[w];
    cnt2[k * NCH + c] = s;
  }
}

// per-offset totals
__global__ __launch_bounds__(512) void k_segtot(const int* __restrict__ cnt2,
                                                int* __restrict__ segs) {
  __shared__ int red[512];
  int k = blockIdx.x, t = threadIdx.x;
  red[t] = (t < NCH) ? cnt2[k * NCH + t] : 0;
  __syncthreads();
  for (int off = 256; off >= 1; off >>= 1) {
    if (t < off) red[t] += red[t + off];
    __syncthreads();
  }
  if (t == 0) segs[k] = red[0];
}

// serial 27-entry base computation (64-padded segments)
__global__ __launch_bounds__(64) void k_segbase(int* __restrict__ segs) {
  if (threadIdx.x == 0) {
    int b = 0;
    for (int k = 0; k < K27; ++k) {
      segs[32 + k] = b;
      b += (segs[k] + 63) & ~63;
    }
    segs[32 + K27] = b;  // total padded pair count
  }
}

// exclusive scan of chunk counts within each offset -> global pair offsets
__global__ __launch_bounds__(512) void k_choff(const int* __restrict__ cnt2,
                                               const int* __restrict__ segs,
                                               int* __restrict__ choff) {
  __shared__ int sc[512];
  int k = blockIdx.x, t = threadIdx.x;
  int v = (t < NCH) ? cnt2[k * NCH + t] : 0;
  sc[t] = v;
  __syncthreads();
  for (int off = 1; off < 512; off <<= 1) {
    int x = (t >= off) ? sc[t - off] : 0;
    __syncthreads();
    sc[t] += x;
    __syncthreads();
  }
  if (t < NCH) choff[k * NCH + t] = segs[32 + k] + sc[t] - v;
}

// emit pairs: in_list[p] = input rank; nbrp (in place) becomes pidx
__global__ __launch_bounds__(512) void k_pairs(int* __restrict__ nbrp,
                                               const int* __restrict__ choff,
                                               int* __restrict__ inl) {
  __shared__ int wsum[8];
  int k = blockIdx.x / NCH, c = blockIdx.x % NCH;
  int j = c * 512 + threadIdx.x;
  int v = (j < N_VOX) ? nbrp[k * N_VOX + j] : -1;
  bool valid = v >= 0;
  unsigned long long bal = __ballot(valid);
  int lane = threadIdx.x & 63, wv = threadIdx.x >> 6;
  int before = __popcll(bal & ((1ull << lane) - 1ull));
  if (lane == 0) wsum[wv] = __popcll(bal);
  __syncthreads();
  int woff = 0;
  #pragma unroll
  for (int w = 0; w < 8; ++w) woff += (w < wv) ? wsum[w] : 0;
  if (valid) {
    int p = choff[k * NCH + c] + woff + before;
    inl[p] = v;
    nbrp[k * N_VOX + j] = p;
  }
}

// 64-pair block -> offset id map
__global__ __launch_bounds__(256) void k_tilek(const int* __restrict__ segs,
                                               int* __restrict__ tile_k) {
  int t = blockIdx.x * 256 + threadIdx.x;
  if (t >= TIL64) return;
  int p0 = t * 64, kk = -1;
  if (p0 < segs[32 + K27]) {
    #pragma unroll 1
    for (int k = 0; k < K27; ++k)
      if (p0 >= segs[32 + k] && p0 < segs[32 + k + 1]) kk = k;
  }
  tile_k[t] = kk;
}

// ---------------- data prep ----------------

__global__ __launch_bounds__(256) void k_gcast(const float* __restrict__ feats,
                                               const int* __restrict__ perm,
                                               ushort* __restrict__ fbp) {
  int i = blockIdx.x * 256 + threadIdx.x;  // N*16 quads
  int j = i >> 4, seg = i & 15;
  int p = perm[j];
  float4 v = reinterpret_cast<const float4*>(feats)[(p << 4) + seg];
  ushort4 o;
  o.x = f2bf(v.x); o.y = f2bf(v.y); o.z = f2bf(v.z); o.w = f2bf(v.w);
  reinterpret_cast<ushort4*>(fbp)[i] = o;
}

// w[k][ci][co] f32 -> packed A-frags for mfma_32x32x16:
// [k][ch(2)][ks(4)][hi1(2)][row32][e8] bf16
__global__ __launch_bounds__(256) void k_castw(const float* __restrict__ w,
                                               ushort* __restrict__ wp) {
  int i = blockIdx.x * 256 + threadIdx.x;
  if (i >= K27 * 4096) return;
  int k = i >> 12, r = i & 4095, ci = r >> 6, co = r & 63;
  int ch = co >> 5, row = co & 31;
  int ks = ci >> 4, hi1 = (ci >> 3) & 1, e = ci & 7;
  int dst = ((((k * 2 + ch) * 4 + ks) * 2 + hi1) << 8) + row * 8 + e;
  wp[dst] = f2bf(w[i]);
}

// ---------------- conv phase A: pair GEMM -> pv ----------------
// block = 256 thr = 2 pair-subtiles x 2 cout-halves; 64 pairs, all same k.
__global__ __launch_bounds__(256, 4) void k_pva(
    const ushort* __restrict__ fin,   // [N][64] bf16 (rank space)
    const ushort* __restrict__ wp,    // packed weight frags
    const int* __restrict__ inl,      // [PAIR_CAP] input ranks (-1 pad)
    const int* __restrict__ tile_k,   // [TIL64]
    ushort* __restrict__ pv) {        // [PAIR_CAP][64]
  const int kk = tile_k[blockIdx.x];
  if (kk < 0) return;
  const int tid = threadIdx.x, lane = tid & 63, wv = tid >> 6;
  const int lo = lane & 31, hi = lane >> 5;
  const int ch = wv & 1, vh = wv >> 1;
  const int pr = blockIdx.x * 64 + vh * 32 + lo;
  const int idx = inl[pr];

  const char* wk = (const char*)wp + (kk << 13) + (ch << 12) + (lane << 4);
  short8 a0 = *(const short8*)(wk);
  short8 a1 = *(const short8*)(wk + 1024);
  short8 a2 = *(const short8*)(wk + 2048);
  short8 a3 = *(const short8*)(wk + 3072);

  short8 b0, b1, b2, b3;
  if (idx >= 0) {
    const char* b = (const char*)fin + ((size_t)idx << 7) + (hi << 4);
    b0 = *(const short8*)(b);
    b1 = *(const short8*)(b + 32);
    b2 = *(const short8*)(b + 64);
    b3 = *(const short8*)(b + 96);
  } else {
    b0 = short8{0,0,0,0,0,0,0,0}; b1 = b0; b2 = b0; b3 = b0;
  }

  floatx16 acc;
  #pragma unroll
  for (int j = 0; j < 16; ++j) acc[j] = 0.f;
  acc = __builtin_amdgcn_mfma_f32_32x32x16_bf16(a0, b0, acc, 0, 0, 0);
  acc = __builtin_amdgcn_mfma_f32_32x32x16_bf16(a1, b1, acc, 0, 0, 0);
  acc = __builtin_amdgcn_mfma_f32_32x32x16_bf16(a2, b2, acc, 0, 0, 0);
  acc = __builtin_amdgcn_mfma_f32_32x32x16_bf16(a3, b3, acc, 0, 0, 0);

  ushort* o = pv + ((size_t)pr << 6) + (ch << 5) + (hi << 2);
  #pragma unroll
  for (int rg = 0; rg < 4; ++rg) {
    ushort4 v;
    v.x = f2bf(acc[rg * 4 + 0]); v.y = f2bf(acc[rg * 4 + 1]);
    v.z = f2bf(acc[rg * 4 + 2]); v.w = f2bf(acc[rg * 4 + 3]);
    *(ushort4*)(o + (rg << 3)) = v;
  }
}

// ---------------- conv phase B: segmented sum + stats ----------------
// block = 256 thr = 32 outputs x 8 lanes (8 channels each).
template <bool OUT_F32>
__global__ __launch_bounds__(256) void k_pvb(
    const ushort* __restrict__ pv,    // [PAIR_CAP][64]
    const int* __restrict__ pidx,     // [27][N] pair ids (-1 invalid)
    const int* __restrict__ perm,     // rank -> orig (for f32 scatter)
    void* __restrict__ fout,
    float* __restrict__ part) {       // [PBB][128]
  __shared__ float sred[4][8][16];
  const int tid = threadIdx.x, lane = tid & 63, wv = tid >> 6;
  const int g = tid >> 3, e = tid & 7;
  const int j = blockIdx.x * 32 + g;

  int p[27];
  #pragma unroll
  for (int t = 0; t < K27; ++t) p[t] = pidx[t * N_VOX + j];

  float acc[8];
  #pragma unroll
  for (int r = 0; r < 8; ++r) acc[r] = 0.f;
  #pragma unroll
  for (int t = 0; t < K27; ++t) {
    if (p[t] >= 0) {
      short8 v = *(const short8*)(pv + ((size_t)p[t] << 6) + (e << 3));
      #pragma unroll
      for (int r = 0; r < 8; ++r) acc[r] += bf2f((ushort)v[r]);
    }
  }

  if (OUT_F32) {
    int pj = perm[j];
    float* o = (float*)fout + ((size_t)pj << 6) + (e << 3);
    float4 v0 = {acc[0], acc[1], acc[2], acc[3]};
    float4 v1 = {acc[4], acc[5], acc[6], acc[7]};
    *(float4*)o = v0;
    *(float4*)(o + 4) = v1;
  } else {
    ushort* o = (ushort*)fout + ((size_t)j << 6) + (e << 3);
    ushort4 v0, v1;
    v0.x = f2bf(acc[0]); v0.y = f2bf(acc[1]);
    v0.z = f2bf(acc[2]); v0.w = f2bf(acc[3]);
    v1.x = f2bf(acc[4]); v1.y = f2bf(acc[5]);
    v1.z = f2bf(acc[6]); v1.w = f2bf(acc[7]);
    *(ushort4*)o = v0;
    *(ushort4*)(o + 4) = v1;
  }

  // stats: reduce over the 8 groups within each wave (lanes stride-8), then LDS
  #pragma unroll
  for (int r = 0; r < 8; ++r) {
    float s = acc[r], ss = acc[r] * acc[r];
    s += __shfl_xor(s, 8);  ss += __shfl_xor(ss, 8);
    s += __shfl_xor(s, 16); ss += __shfl_xor(ss, 16);
    s += __shfl_xor(s, 32); ss += __shfl_xor(ss, 32);
    if (lane < 8) { sred[wv][lane][r] = s; sred[wv][lane][8 + r] = ss; }
  }
  __syncthreads();
  if (tid < 128) {
    int half = tid >> 6, ch = tid & 63;
    int e2 = ch >> 3, r2 = ch & 7;
    float v = sred[0][e2][half * 8 + r2] + sred[1][e2][half * 8 + r2] +
              sred[2][e2][half * 8 + r2] + sred[3][e2][half * 8 + r2];
    part[(size_t)blockIdx.x * 128 + tid] = v;
  }
}

// ---------------- BN / epilogue ----------------

__global__ __launch_bounds__(256) void k_red(const float* __restrict__ part,
                                             float* __restrict__ part2) {
  __shared__ float red[256];
  int tid = threadIdx.x;
  int e = tid & 127, g = tid >> 7;
  float s = 0.f;
  for (int r = blockIdx.x * 2 + g; r < PBB; r += 2 * RBLK)
    s += part[(size_t)r * 128 + e];
  red[tid] = s;
  __syncthreads();
  if (tid < 128) part2[(size_t)blockIdx.x * 128 + tid] = red[tid] + red[tid + 128];
}

__global__ __launch_bounds__(256) void k_bnfin(const float* __restrict__ part2,
                                               const float* __restrict__ gamma,
                                               const float* __restrict__ beta,
                                               float* __restrict__ ab) {
  __shared__ float fin[128];
  int tid = threadIdx.x;
  if (tid < 128) {
    float s = 0.f;
    for (int r = 0; r < RBLK; ++r) s += part2[(size_t)r * 128 + tid];
    fin[tid] = s;
  }
  __syncthreads();
  if (tid < 64) {
    float su = fin[tid], ss = fin[64 + tid];
    float mean = su / (float)N_VOX;
    float var  = ss / (float)N_VOX - mean * mean;
    float a = gamma[tid] * rsqrtf(var + EPSF);
    ab[tid]      = a;
    ab[64 + tid] = beta[tid] - mean * a;
  }
}

__global__ __launch_bounds__(256) void k_bnrelu8(ushort* __restrict__ x,
                                                 const float* __restrict__ ab) {
  int i = blockIdx.x * 256 + threadIdx.x;  // N*8 groups
  ushort4 v0 = reinterpret_cast<ushort4*>(x)[i * 2];
  ushort4 v1 = reinterpret_cast<ushort4*>(x)[i * 2 + 1];
  int cb = (i * 8) & 63;
  v0.x = f2bf(fmaxf(bf2f(v0.x) * ab[cb]     + ab[64 + cb],     0.f));
  v0.y = f2bf(fmaxf(bf2f(v0.y) * ab[cb + 1] + ab[64 + cb + 1], 0.f));
  v0.z = f2bf(fmaxf(bf2f(v0.z) * ab[cb + 2] + ab[64 + cb + 2], 0.f));
  v0.w = f2bf(fmaxf(bf2f(v0.w) * ab[cb + 3] + ab[64 + cb + 3], 0.f));
  v1.x = f2bf(fmaxf(bf2f(v1.x) * ab[cb + 4] + ab[64 + cb + 4], 0.f));
  v1.y = f2bf(fmaxf(bf2f(v1.y) * ab[cb + 5] + ab[64 + cb + 5], 0.f));
  v1.z = f2bf(fmaxf(bf2f(v1.z) * ab[cb + 6] + ab[64 + cb + 6], 0.f));
  v1.w = f2bf(fmaxf(bf2f(v1.w) * ab[cb + 7] + ab[64 + cb + 7], 0.f));
  reinterpret_cast<ushort4*>(x)[i * 2]     = v0;
  reinterpret_cast<ushort4*>(x)[i * 2 + 1] = v1;
}

__global__ __launch_bounds__(256) void k_final4(float* __restrict__ h2,
                                                const float* __restrict__ feats,
                                                const float* __restrict__ ab) {
  int i = blockIdx.x * 256 + threadIdx.x;
  float4 a = reinterpret_cast<float4*>(h2)[i];
  float4 f = reinterpret_cast<const float4*>(feats)[i];
  int cb = (i * 4) & 63;
  float4 o;
  o.x = fmaxf(a.x * ab[cb]     + ab[64 + cb]     + f.x, 0.f);
  o.y = fmaxf(a.y * ab[cb + 1] + ab[64 + cb + 1] + f.y, 0.f);
  o.z = fmaxf(a.z * ab[cb + 2] + ab[64 + cb + 2] + f.z, 0.f);
  o.w = fmaxf(a.w * ab[cb + 3] + ab[64 + cb + 3] + f.w, 0.f);
  reinterpret_cast<float4*>(h2)[i] = o;
}

extern "C" void kernel_launch(void* const* d_in, const int* in_sizes, int n_in,
                              void* d_out, int out_size, void* d_ws, size_t ws_size,
                              hipStream_t stream) {
  const float* feats  = (const float*)d_in[0];
  const float* w1     = (const float*)d_in[1];
  const float* g1     = (const float*)d_in[2];
  const float* b1     = (const float*)d_in[3];
  const float* w2     = (const float*)d_in[4];
  const float* g2     = (const float*)d_in[5];
  const float* b2     = (const float*)d_in[6];
  const int*   coords = (const int*)d_in[7];
  float* out = (float*)d_out;

  char* ws = (char*)d_ws;
  ushort* pv    = (ushort*)ws;  ws += (size_t)PAIR_CAP * C * 2;    // 58.9 MB
  int*    table = (int*)ws;     ws += (size_t)TBL_N * 4;           // 16.8 MB
  int*    nbrp  = (int*)ws;     ws += (size_t)K27 * N_VOX * 4;     // 21.6 MB
  ushort* fbp   = (ushort*)ws;  ws += (size_t)N_VOX * C * 2;       // 25.6 MB
  ushort* h1p   = (ushort*)ws;  ws += (size_t)N_VOX * C * 2;       // 25.6 MB
  int*    perm  = (int*)ws;     ws += (size_t)N_VOX * 4;
  ushort* wp1   = (ushort*)ws;  ws += (size_t)K27 * 4096 * 2;
  ushort* wp2   = (ushort*)ws;  ws += (size_t)K27 * 4096 * 2;
  int*    inl   = (int*)ws;     ws += (size_t)PAIR_CAP * 4;
  int*    bsum  = (int*)ws;     ws += 4096 * 4;
  int*    boff  = (int*)ws;     ws += 4096 * 4;
  int*    cnt2  = (int*)ws;     ws += 42240;
  int*    choff = (int*)ws;     ws += 42240;
  int*    segs  = (int*)ws;     ws += 256;
  int*    tilk  = (int*)ws;     ws += (size_t)TIL64 * 4;
  float*  part2 = (float*)ws;   ws += (size_t)RBLK * 128 * 4;
  float*  ab1   = (float*)ws;   ws += 512;
  float*  ab2   = (float*)ws;   ws += 512;
  float*  part  = (float*)table;  // alias: table dead after k_nbrp

  // rulebook
  k_fill<<<TBL_N / 256, 256, 0, stream>>>(table, bsum, inl);
  k_scatter<<<(N_VOX + 255) / 256, 256, 0, stream>>>(coords, table);
  k_count<<<(N_VOX + 255) / 256, 256, 0, stream>>>(coords, bsum);
  k_scan<<<1, 1024, 0, stream>>>(bsum, boff);
  k_compact<<<TBL_N / 1024, 1024, 0, stream>>>(table, boff, perm);
  k_nbrp<<<(N_VOX + 255) / 256, 256, 0, stream>>>(coords, table, perm, nbrp);
  k_cnt2b<<<K27 * NCH, 512, 0, stream>>>(nbrp, cnt2);
  k_segtot<<<K27, 512, 0, stream>>>(cnt2, segs);
  k_segbase<<<1, 64, 0, stream>>>(segs);
  k_choff<<<K27, 512, 0, stream>>>(cnt2, segs, choff);
  k_pairs<<<K27 * NCH, 512, 0, stream>>>(nbrp, choff, inl);
  k_tilek<<<(TIL64 + 255) / 256, 256, 0, stream>>>(segs, tilk);

  // data prep
  k_gcast<<<N_VOX * 16 / 256, 256, 0, stream>>>(feats, perm, fbp);
  k_castw<<<(K27 * 4096 + 255) / 256, 256, 0, stream>>>(w1, wp1);
  k_castw<<<(K27 * 4096 + 255) / 256, 256, 0, stream>>>(w2, wp2);

  // conv1
  k_pva<<<TIL64, 256, 0, stream>>>(fbp, wp1, inl, tilk, pv);
  k_pvb<false><<<PBB, 256, 0, stream>>>(pv, nbrp, perm, h1p, part);
  k_red<<<RBLK, 256, 0, stream>>>(part, part2);
  k_bnfin<<<1, 256, 0, stream>>>(part2, g1, b1, ab1);
  k_bnrelu8<<<N_VOX * 8 / 256, 256, 0, stream>>>(h1p, ab1);

  // conv2
  k_pva<<<TIL64, 256, 0, stream>>>(h1p, wp2, inl, tilk, pv);
  k_pvb<true><<<PBB, 256, 0, stream>>>(pv, nbrp, perm, out, part);
  k_red<<<RBLK, 256, 0, stream>>>(part, part2);
  k_bnfin<<<1, 256, 0, stream>>>(part2, g2, b2, ab2);
  k_final4<<<N_VOX * 64 / 4 / 256, 256, 0, stream>>>(out, feats, ab2);
}

// Round 8
// 298.572 us; speedup vs baseline: 1.7176x; 1.0418x over previous
//
#include <hip/hip_runtime.h>

// SparseResBlock on MI355X — round 7: round-6 spconv structure with pass and
// launch fusion: BN1+ReLU folded into conv2 gather, pair counting folded into
// nbr build, bf16 linear conv outputs, BN2+residual in gather/scatter final.

constexpr int N_VOX = 200000;
constexpr int GEXT  = 128;
constexpr int C     = 64;
constexpr int K27   = 27;
constexpr int TBL_N = 2 * GEXT * GEXT * GEXT;  // 4,194,304
constexpr float EPSF = 1e-5f;

constexpr int NCH      = 782;               // ceil(N/256) chunks per offset
constexpr int PAIR_CAP = 460032;            // > expected ~448k pairs, mult of 64
constexpr int TIL64    = PAIR_CAP / 64;     // 7188
constexpr int PBB      = 6250;              // phase-B blocks (32 outputs each)
constexpr int RBLK     = 128;               // stage-1 reduce blocks

using short8   = __attribute__((ext_vector_type(8))) short;
using floatx16 = __attribute__((ext_vector_type(16))) float;

static __device__ __forceinline__ ushort f2bf(float f) {
  union { float f; unsigned u; } a; a.f = f;
  unsigned r = a.u + 0x7fff + ((a.u >> 16) & 1);  // RTNE
  return (ushort)(r >> 16);
}
static __device__ __forceinline__ float bf2f(ushort h) {
  union { unsigned u; float f; } a; a.u = ((unsigned)h) << 16;
  return a.f;
}

// ---------------- rulebook build ----------------

__global__ __launch_bounds__(256) void k_fill(int* __restrict__ t,
                                              int* __restrict__ bsum,
                                              int* __restrict__ inl) {
  int i = blockIdx.x * 256 + threadIdx.x;
  if (i < TBL_N) t[i] = -1;
  if (i < 4096) bsum[i] = 0;
  if (i < PAIR_CAP) inl[i] = -1;
}

__global__ __launch_bounds__(256) void k_scatcnt(const int* __restrict__ coords,
                                                 int* __restrict__ t,
                                                 int* __restrict__ bsum) {
  int n = blockIdx.x * 256 + threadIdx.x;
  if (n >= N_VOX) return;
  int4 c = reinterpret_cast<const int4*>(coords)[n];
  int lin = ((c.x * GEXT + c.y) * GEXT + c.z) * GEXT + c.w;
  t[lin] = n;
  atomicAdd(&bsum[lin >> 10], 1);
}

__global__ __launch_bounds__(1024) void k_scan(const int* __restrict__ bsum,
                                               int* __restrict__ boff) {
  __shared__ int sc[1024];
  int t = threadIdx.x;
  int v0 = bsum[t * 4], v1 = bsum[t * 4 + 1], v2 = bsum[t * 4 + 2],
      v3 = bsum[t * 4 + 3];
  int s = v0 + v1 + v2 + v3;
  sc[t] = s;
  __syncthreads();
  for (int off = 1; off < 1024; off <<= 1) {
    int x = (t >= off) ? sc[t - off] : 0;
    __syncthreads();
    sc[t] += x;
    __syncthreads();
  }
  int excl = sc[t] - s;
  boff[t * 4]     = excl;
  boff[t * 4 + 1] = excl + v0;
  boff[t * 4 + 2] = excl + v0 + v1;
  boff[t * 4 + 3] = excl + v0 + v1 + v2;
}

__global__ __launch_bounds__(1024) void k_compact(int* __restrict__ table,
                                                  const int* __restrict__ boff,
                                                  int* __restrict__ perm) {
  __shared__ int wsum[16];
  int i = blockIdx.x * 1024 + threadIdx.x;
  int orig = table[i];
  bool valid = orig >= 0;
  unsigned long long bal = __ballot(valid);
  int lane = threadIdx.x & 63, wv = threadIdx.x >> 6;
  int before = __popcll(bal & ((1ull << lane) - 1ull));
  if (lane == 0) wsum[wv] = __popcll(bal);
  __syncthreads();
  int woff = 0;
  for (int w = 0; w < 16; ++w) woff += (w < wv) ? wsum[w] : 0;
  if (valid) {
    int j = boff[blockIdx.x] + woff + before;
    perm[j] = orig;
    table[i] = j;
  }
}

// neighbor ranks + per-(k,chunk) pair counts (ballot, no atomics)
__global__ __launch_bounds__(256) void k_nbrc(const int* __restrict__ coords,
                                              const int* __restrict__ table,
                                              const int* __restrict__ perm,
                                              int* __restrict__ nbrp,
                                              int* __restrict__ cnt2) {
  __shared__ int wcnt[27][4];
  int tid = threadIdx.x;
  int j = blockIdx.x * 256 + tid;
  bool on = j < N_VOX;
  int4 c = {0, 0, 0, 0};
  if (on) {
    int orig = perm[j];
    c = reinterpret_cast<const int4*>(coords)[orig];
  }
  int k = 0;
  #pragma unroll
  for (int dx = -1; dx <= 1; ++dx)
    #pragma unroll
    for (int dy = -1; dy <= 1; ++dy)
      #pragma unroll
      for (int dz = -1; dz <= 1; ++dz) {
        int rank = -1;
        if (on) {
          int x = c.y + dx, y = c.z + dy, z = c.w + dz;
          if (((unsigned)x < (unsigned)GEXT) & ((unsigned)y < (unsigned)GEXT) &
              ((unsigned)z < (unsigned)GEXT)) {
            int lin = ((c.x * GEXT + x) * GEXT + y) * GEXT + z;
            rank = table[lin];
          }
          nbrp[k * N_VOX + j] = rank;
        }
        unsigned long long bal = __ballot(rank >= 0);
        if ((tid & 63) == 0) wcnt[k][tid >> 6] = __popcll(bal);
        ++k;
      }
  __syncthreads();
  if (tid < 27)
    cnt2[tid * NCH + blockIdx.x] =
        wcnt[tid][0] + wcnt[tid][1] + wcnt[tid][2] + wcnt[tid][3];
}

// per-offset chunk-count scan (relative) + per-offset totals
__global__ __launch_bounds__(256) void k_segscan(const int* __restrict__ cnt2,
                                                 int* __restrict__ choff,
                                                 int* __restrict__ segs) {
  __shared__ int sc[256];
  int k = blockIdx.x, t = threadIdx.x;
  int v[4];
  #pragma unroll
  for (int i = 0; i < 4; ++i) {
    int idx = t * 4 + i;
    v[i] = (idx < NCH) ? cnt2[k * NCH + idx] : 0;
  }
  int s = v[0] + v[1] + v[2] + v[3];
  sc[t] = s;
  __syncthreads();
  for (int off = 1; off < 256; off <<= 1) {
    int x = (t >= off) ? sc[t - off] : 0;
    __syncthreads();
    sc[t] += x;
    __syncthreads();
  }
  int run = sc[t] - s;
  #pragma unroll
  for (int i = 0; i < 4; ++i) {
    int idx = t * 4 + i;
    if (idx < NCH) choff[k * NCH + idx] = run;
    run += v[i];
  }
  if (t == 255) segs[k] = sc[255];
}

// bases (serial 27) + tile->k map, one block
__global__ __launch_bounds__(1024) void k_tiles(int* __restrict__ segs,
                                                int* __restrict__ tile_k) {
  __shared__ int sb[28];
  if (threadIdx.x == 0) {
    int b = 0;
    for (int k = 0; k < K27; ++k) {
      sb[k] = b;
      segs[32 + k] = b;
      b += (segs[k] + 63) & ~63;
    }
    sb[27] = b;
    segs[32 + K27] = b;
  }
  __syncthreads();
  for (int t = threadIdx.x; t < TIL64; t += 1024) {
    int p0 = t * 64, kk = -1;
    #pragma unroll 1
    for (int k = 0; k < K27; ++k)
      if (p0 >= sb[k] && p0 < sb[k + 1]) kk = k;
    tile_k[t] = kk;
  }
}

// emit pairs: inl[p] = input rank; nbrp (in place) becomes pidx
__global__ __launch_bounds__(256) void k_pairs(int* __restrict__ nbrp,
                                               const int* __restrict__ choff,
                                               const int* __restrict__ segs,
                                               int* __restrict__ inl) {
  __shared__ int wsum[4];
  int k = blockIdx.x / NCH, cch = blockIdx.x % NCH;
  int j = cch * 256 + threadIdx.x;
  int v = (j < N_VOX) ? nbrp[k * N_VOX + j] : -1;
  bool valid = v >= 0;
  unsigned long long bal = __ballot(valid);
  int lane = threadIdx.x & 63, wv = threadIdx.x >> 6;
  int before = __popcll(bal & ((1ull << lane) - 1ull));
  if (lane == 0) wsum[wv] = __popcll(bal);
  __syncthreads();
  int woff = 0;
  #pragma unroll
  for (int w = 0; w < 4; ++w) woff += (w < wv) ? wsum[w] : 0;
  if (valid) {
    int p = segs[32 + k] + choff[k * NCH + cch] + woff + before;
    inl[p] = v;
    nbrp[k * N_VOX + j] = p;
  }
}

// ---------------- data prep (fused gcast + castw1 + castw2) ----------------

__global__ __launch_bounds__(256) void k_prep(const float* __restrict__ feats,
                                              const int* __restrict__ perm,
                                              const float* __restrict__ w1,
                                              const float* __restrict__ w2,
                                              ushort* __restrict__ fbp,
                                              ushort* __restrict__ wp1,
                                              ushort* __restrict__ wp2) {
  int b = blockIdx.x;
  if (b < 12500) {  // feats gather-cast: N*16 float4 groups
    int i = b * 256 + threadIdx.x;
    int j = i >> 4, seg = i & 15;
    int p = perm[j];
    float4 v = reinterpret_cast<const float4*>(feats)[(p << 4) + seg];
    ushort4 o;
    o.x = f2bf(v.x); o.y = f2bf(v.y); o.z = f2bf(v.z); o.w = f2bf(v.w);
    reinterpret_cast<ushort4*>(fbp)[i] = o;
  } else {          // weight pack: [k][ch][ks][hi1][row32][e8]
    const float* w = (b < 12932) ? w1 : w2;
    ushort* wp = (b < 12932) ? wp1 : wp2;
    int i = (b - (b < 12932 ? 12500 : 12932)) * 256 + threadIdx.x;
    int k = i >> 12, r = i & 4095, ci = r >> 6, co = r & 63;
    int ch = co >> 5, row = co & 31;
    int ks = ci >> 4, hi1 = (ci >> 3) & 1, e = ci & 7;
    int dst = ((((k * 2 + ch) * 4 + ks) * 2 + hi1) << 8) + row * 8 + e;
    wp[dst] = f2bf(w[i]);
  }
}

// ---------------- conv phase A: pair GEMM -> pv ----------------
// APPLY_BN: apply BN1+ReLU (scale/shift from ab, LDS) to gathered rows.
template <bool APPLY_BN>
__global__ __launch_bounds__(256, 4) void k_pva(
    const ushort* __restrict__ fin,   // [N][64] bf16 (rank space)
    const ushort* __restrict__ wp,    // packed weight frags
    const int* __restrict__ inl,      // [PAIR_CAP] input ranks (-1 pad)
    const int* __restrict__ tile_k,   // [TIL64]
    const float* __restrict__ ab,     // [128] scale/shift (APPLY_BN)
    ushort* __restrict__ pv) {        // [PAIR_CAP][64]
  __shared__ float abl[128];
  const int kk = tile_k[blockIdx.x];
  const int tid = threadIdx.x;
  if (APPLY_BN) {
    if (tid < 128) abl[tid] = ab[tid];
    __syncthreads();
  }
  if (kk < 0) return;
  const int lane = tid & 63, wv = tid >> 6;
  const int lo = lane & 31, hi = lane >> 5;
  const int ch = wv & 1, vh = wv >> 1;
  const int pr = blockIdx.x * 64 + vh * 32 + lo;
  const int idx = inl[pr];

  const char* wk = (const char*)wp + (kk << 13) + (ch << 12) + (lane << 4);
  short8 a0 = *(const short8*)(wk);
  short8 a1 = *(const short8*)(wk + 1024);
  short8 a2 = *(const short8*)(wk + 2048);
  short8 a3 = *(const short8*)(wk + 3072);

  short8 b0, b1, b2, b3;
  if (idx >= 0) {
    const char* b = (const char*)fin + ((size_t)idx << 7) + (hi << 4);
    b0 = *(const short8*)(b);
    b1 = *(const short8*)(b + 32);
    b2 = *(const short8*)(b + 64);
    b3 = *(const short8*)(b + 96);
    if (APPLY_BN) {
      #pragma unroll
      for (int ks = 0; ks < 4; ++ks) {
        short8& v = ks == 0 ? b0 : ks == 1 ? b1 : ks == 2 ? b2 : b3;
        int cb = ks * 16 + hi * 8;
        #pragma unroll
        for (int e = 0; e < 8; ++e) {
          float x = bf2f((ushort)v[e]);
          x = fmaxf(x * abl[cb + e] + abl[64 + cb + e], 0.f);
          v[e] = (short)f2bf(x);
        }
      }
    }
  } else {
    b0 = short8{0,0,0,0,0,0,0,0}; b1 = b0; b2 = b0; b3 = b0;
  }

  floatx16 acc;
  #pragma unroll
  for (int j = 0; j < 16; ++j) acc[j] = 0.f;
  acc = __builtin_amdgcn_mfma_f32_32x32x16_bf16(a0, b0, acc, 0, 0, 0);
  acc = __builtin_amdgcn_mfma_f32_32x32x16_bf16(a1, b1, acc, 0, 0, 0);
  acc = __builtin_amdgcn_mfma_f32_32x32x16_bf16(a2, b2, acc, 0, 0, 0);
  acc = __builtin_amdgcn_mfma_f32_32x32x16_bf16(a3, b3, acc, 0, 0, 0);

  ushort* o = pv + ((size_t)pr << 6) + (ch << 5) + (hi << 2);
  #pragma unroll
  for (int rg = 0; rg < 4; ++rg) {
    ushort4 v;
    v.x = f2bf(acc[rg * 4 + 0]); v.y = f2bf(acc[rg * 4 + 1]);
    v.z = f2bf(acc[rg * 4 + 2]); v.w = f2bf(acc[rg * 4 + 3]);
    *(ushort4*)(o + (rg << 3)) = v;
  }
}

// ---------------- conv phase B: segmented sum + stats ----------------
// block = 256 thr = 32 outputs x 8 lanes; writes raw conv bf16 (rank order).
__global__ __launch_bounds__(256) void k_pvb(
    const ushort* __restrict__ pv,    // [PAIR_CAP][64]
    const int* __restrict__ pidx,     // [27][N] pair ids (-1 invalid)
    ushort* __restrict__ fout,        // [N][64] bf16
    float* __restrict__ part) {       // [PBB][128]
  __shared__ float sred[4][8][16];
  const int tid = threadIdx.x, lane = tid & 63, wv = tid >> 6;
  const int g = tid >> 3, e = tid & 7;
  const int j = blockIdx.x * 32 + g;

  int p[27];
  #pragma unroll
  for (int t = 0; t < K27; ++t) p[t] = pidx[t * N_VOX + j];

  float acc[8];
  #pragma unroll
  for (int r = 0; r < 8; ++r) acc[r] = 0.f;
  #pragma unroll
  for (int t = 0; t < K27; ++t) {
    if (p[t] >= 0) {
      short8 v = *(const short8*)(pv + ((size_t)p[t] << 6) + (e << 3));
      #pragma unroll
      for (int r = 0; r < 8; ++r) acc[r] += bf2f((ushort)v[r]);
    }
  }

  ushort* o = fout + ((size_t)j << 6) + (e << 3);
  ushort4 v0, v1;
  v0.x = f2bf(acc[0]); v0.y = f2bf(acc[1]);
  v0.z = f2bf(acc[2]); v0.w = f2bf(acc[3]);
  v1.x = f2bf(acc[4]); v1.y = f2bf(acc[5]);
  v1.z = f2bf(acc[6]); v1.w = f2bf(acc[7]);
  *(ushort4*)o = v0;
  *(ushort4*)(o + 4) = v1;

  #pragma unroll
  for (int r = 0; r < 8; ++r) {
    float s = acc[r], ss = acc[r] * acc[r];
    s += __shfl_xor(s, 8);  ss += __shfl_xor(ss, 8);
    s += __shfl_xor(s, 16); ss += __shfl_xor(ss, 16);
    s += __shfl_xor(s, 32); ss += __shfl_xor(ss, 32);
    if (lane < 8) { sred[wv][lane][r] = s; sred[wv][lane][8 + r] = ss; }
  }
  __syncthreads();
  if (tid < 128) {
    int half = tid >> 6, chn = tid & 63;
    int e2 = chn >> 3, r2 = chn & 7;
    float v = sred[0][e2][half * 8 + r2] + sred[1][e2][half * 8 + r2] +
              sred[2][e2][half * 8 + r2] + sred[3][e2][half * 8 + r2];
    part[(size_t)blockIdx.x * 128 + tid] = v;
  }
}

// ---------------- BN / epilogue ----------------

__global__ __launch_bounds__(256) void k_red(const float* __restrict__ part,
                                             float* __restrict__ part2) {
  __shared__ float red[256];
  int tid = threadIdx.x;
  int e = tid & 127, g = tid >> 7;
  float s = 0.f;
  for (int r = blockIdx.x * 2 + g; r < PBB; r += 2 * RBLK)
    s += part[(size_t)r * 128 + e];
  red[tid] = s;
  __syncthreads();
  if (tid < 128) part2[(size_t)blockIdx.x * 128 + tid] = red[tid] + red[tid + 128];
}

__global__ __launch_bounds__(256) void k_bnfin(const float* __restrict__ part2,
                                               const float* __restrict__ gamma,
                                               const float* __restrict__ beta,
                                               float* __restrict__ ab) {
  __shared__ float fin[128];
  int tid = threadIdx.x;
  if (tid < 128) {
    float s = 0.f;
    for (int r = 0; r < RBLK; ++r) s += part2[(size_t)r * 128 + tid];
    fin[tid] = s;
  }
  __syncthreads();
  if (tid < 64) {
    float su = fin[tid], ss = fin[64 + tid];
    float mean = su / (float)N_VOX;
    float var  = ss / (float)N_VOX - mean * mean;
    float a = gamma[tid] * rsqrtf(var + EPSF);
    ab[tid]      = a;
    ab[64 + tid] = beta[tid] - mean * a;
  }
}

// BN2 + residual + ReLU: gather feats / scatter out via perm, read h2p linear
__global__ __launch_bounds__(256) void k_final(const ushort* __restrict__ h2p,
                                               const float* __restrict__ feats,
                                               const int* __restrict__ perm,
                                               const float* __restrict__ ab,
                                               float* __restrict__ out) {
  int i = blockIdx.x * 256 + threadIdx.x;  // N*16 float4 groups
  int j = i >> 4, seg = i & 15;
  int p = perm[j];
  ushort4 h = reinterpret_cast<const ushort4*>(h2p)[i];
  float4 f = reinterpret_cast<const float4*>(feats)[(p << 4) + seg];
  int cb = seg * 4;
  float4 o;
  o.x = fmaxf(bf2f(h.x) * ab[cb]     + ab[64 + cb]     + f.x, 0.f);
  o.y = fmaxf(bf2f(h.y) * ab[cb + 1] + ab[64 + cb + 1] + f.y, 0.f);
  o.z = fmaxf(bf2f(h.z) * ab[cb + 2] + ab[64 + cb + 2] + f.z, 0.f);
  o.w = fmaxf(bf2f(h.w) * ab[cb + 3] + ab[64 + cb + 3] + f.w, 0.f);
  reinterpret_cast<float4*>(out)[(p << 4) + seg] = o;
}

extern "C" void kernel_launch(void* const* d_in, const int* in_sizes, int n_in,
                              void* d_out, int out_size, void* d_ws, size_t ws_size,
                              hipStream_t stream) {
  const float* feats  = (const float*)d_in[0];
  const float* w1     = (const float*)d_in[1];
  const float* g1     = (const float*)d_in[2];
  const float* b1     = (const float*)d_in[3];
  const float* w2     = (const float*)d_in[4];
  const float* g2     = (const float*)d_in[5];
  const float* b2     = (const float*)d_in[6];
  const int*   coords = (const int*)d_in[7];
  float* out = (float*)d_out;

  char* ws = (char*)d_ws;
  ushort* pv    = (ushort*)ws;  ws += (size_t)PAIR_CAP * C * 2;    // 58.9 MB
  int*    table = (int*)ws;     ws += (size_t)TBL_N * 4;           // 16.8 MB
  int*    nbrp  = (int*)ws;     ws += (size_t)K27 * N_VOX * 4;     // 21.6 MB
  ushort* fbp   = (ushort*)ws;  ws += (size_t)N_VOX * C * 2;       // 25.6 MB
  ushort* h1p   = (ushort*)ws;  ws += (size_t)N_VOX * C * 2;       // 25.6 MB
  int*    perm  = (int*)ws;     ws += (size_t)N_VOX * 4;
  ushort* wp1   = (ushort*)ws;  ws += (size_t)K27 * 4096 * 2;
  ushort* wp2   = (ushort*)ws;  ws += (size_t)K27 * 4096 * 2;
  int*    inl   = (int*)ws;     ws += (size_t)PAIR_CAP * 4;
  int*    bsum  = (int*)ws;     ws += 4096 * 4;
  int*    boff  = (int*)ws;     ws += 4096 * 4;
  int*    cnt2  = (int*)ws;     ws += (size_t)K27 * NCH * 4;
  int*    choff = (int*)ws;     ws += (size_t)K27 * NCH * 4;
  int*    segs  = (int*)ws;     ws += 256;
  int*    tilk  = (int*)ws;     ws += (size_t)TIL64 * 4;
  float*  part2 = (float*)ws;   ws += (size_t)RBLK * 128 * 4;
  float*  ab1   = (float*)ws;   ws += 512;
  float*  ab2   = (float*)ws;   ws += 512;
  float*  part  = (float*)table;   // alias: table dead after k_nbrc
  ushort* h2p   = fbp;             // alias: fbp dead after conv1 phase A

  // rulebook
  k_fill<<<TBL_N / 256, 256, 0, stream>>>(table, bsum, inl);
  k_scatcnt<<<(N_VOX + 255) / 256, 256, 0, stream>>>(coords, table, bsum);
  k_scan<<<1, 1024, 0, stream>>>(bsum, boff);
  k_compact<<<TBL_N / 1024, 1024, 0, stream>>>(table, boff, perm);
  k_nbrc<<<NCH, 256, 0, stream>>>(coords, table, perm, nbrp, cnt2);
  k_segscan<<<K27, 256, 0, stream>>>(cnt2, choff, segs);
  k_tiles<<<1, 1024, 0, stream>>>(segs, tilk);
  k_pairs<<<K27 * NCH, 256, 0, stream>>>(nbrp, choff, segs, inl);

  // data prep (gcast + both weight packs)
  k_prep<<<13364, 256, 0, stream>>>(feats, perm, w1, w2, fbp, wp1, wp2);

  // conv1 (raw conv output -> h1p bf16; stats fused)
  k_pva<false><<<TIL64, 256, 0, stream>>>(fbp, wp1, inl, tilk, ab1, pv);
  k_pvb<<<PBB, 256, 0, stream>>>(pv, nbrp, h1p, part);
  k_red<<<RBLK, 256, 0, stream>>>(part, part2);
  k_bnfin<<<1, 256, 0, stream>>>(part2, g1, b1, ab1);

  // conv2 (BN1+ReLU applied during gather; raw conv2 -> h2p bf16)
  k_pva<true><<<TIL64, 256, 0, stream>>>(h1p, wp2, inl, tilk, ab1, pv);
  k_pvb<<<PBB, 256, 0, stream>>>(pv, nbrp, h2p, part);
  k_red<<<RBLK, 256, 0, stream>>>(part, part2);
  k_bnfin<<<1, 256, 0, stream>>>(part2, g2, b2, ab2);

  // BN2 + residual + ReLU -> d_out (original order)
  k_final<<<N_VOX * 16 / 256, 256, 0, stream>>>(h2p, feats, perm, ab2, out);
}

// Round 9
// 277.347 us; speedup vs baseline: 1.8491x; 1.0765x over previous
//
#include <hip/hip_runtime.h>

// SparseResBlock on MI355X — round 8: round-7 spconv pipeline with
// (1) LDS-staged coalesced pv writes in phase A + inline tile->k mapping,
// (2) k_prep merged into k_pairs, (3) bf16 residual in k_final.

constexpr int N_VOX = 200000;
constexpr int GEXT  = 128;
constexpr int C     = 64;
constexpr int K27   = 27;
constexpr int TBL_N = 2 * GEXT * GEXT * GEXT;  // 4,194,304
constexpr float EPSF = 1e-5f;

constexpr int NCH      = 782;               // ceil(N/256) chunks per offset
constexpr int PAIR_CAP = 460032;            // > expected ~448k pairs, mult of 64
constexpr int TIL64    = PAIR_CAP / 64;     // 7188
constexpr int PBB      = 6250;              // phase-B blocks (32 outputs each)
constexpr int RBLK     = 128;               // stage-1 reduce blocks
constexpr int PAIRS_BLKS = K27 * NCH;       // 21114
constexpr int PREP_FEAT  = 12500;           // N*16/256
constexpr int PREP_W     = 432;             // 27*4096/256

using short8   = __attribute__((ext_vector_type(8))) short;
using floatx16 = __attribute__((ext_vector_type(16))) float;

static __device__ __forceinline__ ushort f2bf(float f) {
  union { float f; unsigned u; } a; a.f = f;
  unsigned r = a.u + 0x7fff + ((a.u >> 16) & 1);  // RTNE
  return (ushort)(r >> 16);
}
static __device__ __forceinline__ float bf2f(ushort h) {
  union { unsigned u; float f; } a; a.u = ((unsigned)h) << 16;
  return a.f;
}

// ---------------- rulebook build ----------------

__global__ __launch_bounds__(256) void k_fill(int* __restrict__ t,
                                              int* __restrict__ bsum) {
  int i = blockIdx.x * 256 + threadIdx.x;
  if (i < TBL_N) t[i] = -1;
  if (i < 4096) bsum[i] = 0;
}

__global__ __launch_bounds__(256) void k_scatcnt(const int* __restrict__ coords,
                                                 int* __restrict__ t,
                                                 int* __restrict__ bsum) {
  int n = blockIdx.x * 256 + threadIdx.x;
  if (n >= N_VOX) return;
  int4 c = reinterpret_cast<const int4*>(coords)[n];
  int lin = ((c.x * GEXT + c.y) * GEXT + c.z) * GEXT + c.w;
  t[lin] = n;
  atomicAdd(&bsum[lin >> 10], 1);
}

__global__ __launch_bounds__(1024) void k_scan(const int* __restrict__ bsum,
                                               int* __restrict__ boff) {
  __shared__ int sc[1024];
  int t = threadIdx.x;
  int v0 = bsum[t * 4], v1 = bsum[t * 4 + 1], v2 = bsum[t * 4 + 2],
      v3 = bsum[t * 4 + 3];
  int s = v0 + v1 + v2 + v3;
  sc[t] = s;
  __syncthreads();
  for (int off = 1; off < 1024; off <<= 1) {
    int x = (t >= off) ? sc[t - off] : 0;
    __syncthreads();
    sc[t] += x;
    __syncthreads();
  }
  int excl = sc[t] - s;
  boff[t * 4]     = excl;
  boff[t * 4 + 1] = excl + v0;
  boff[t * 4 + 2] = excl + v0 + v1;
  boff[t * 4 + 3] = excl + v0 + v1 + v2;
}

__global__ __launch_bounds__(1024) void k_compact(int* __restrict__ table,
                                                  const int* __restrict__ boff,
                                                  int* __restrict__ perm) {
  __shared__ int wsum[16];
  int i = blockIdx.x * 1024 + threadIdx.x;
  int orig = table[i];
  bool valid = orig >= 0;
  unsigned long long bal = __ballot(valid);
  int lane = threadIdx.x & 63, wv = threadIdx.x >> 6;
  int before = __popcll(bal & ((1ull << lane) - 1ull));
  if (lane == 0) wsum[wv] = __popcll(bal);
  __syncthreads();
  int woff = 0;
  for (int w = 0; w < 16; ++w) woff += (w < wv) ? wsum[w] : 0;
  if (valid) {
    int j = boff[blockIdx.x] + woff + before;
    perm[j] = orig;
    table[i] = j;
  }
}

// neighbor ranks + per-(k,chunk) pair counts (ballot, no atomics)
__global__ __launch_bounds__(256) void k_nbrc(const int* __restrict__ coords,
                                              const int* __restrict__ table,
                                              const int* __restrict__ perm,
                                              int* __restrict__ nbrp,
                                              int* __restrict__ cnt2) {
  __shared__ int wcnt[27][4];
  int tid = threadIdx.x;
  int j = blockIdx.x * 256 + tid;
  bool on = j < N_VOX;
  int4 c = {0, 0, 0, 0};
  if (on) {
    int orig = perm[j];
    c = reinterpret_cast<const int4*>(coords)[orig];
  }
  int k = 0;
  #pragma unroll
  for (int dx = -1; dx <= 1; ++dx)
    #pragma unroll
    for (int dy = -1; dy <= 1; ++dy)
      #pragma unroll
      for (int dz = -1; dz <= 1; ++dz) {
        int rank = -1;
        if (on) {
          int x = c.y + dx, y = c.z + dy, z = c.w + dz;
          if (((unsigned)x < (unsigned)GEXT) & ((unsigned)y < (unsigned)GEXT) &
              ((unsigned)z < (unsigned)GEXT)) {
            int lin = ((c.x * GEXT + x) * GEXT + y) * GEXT + z;
            rank = table[lin];
          }
          nbrp[k * N_VOX + j] = rank;
        }
        unsigned long long bal = __ballot(rank >= 0);
        if ((tid & 63) == 0) wcnt[k][tid >> 6] = __popcll(bal);
        ++k;
      }
  __syncthreads();
  if (tid < 27)
    cnt2[tid * NCH + blockIdx.x] =
        wcnt[tid][0] + wcnt[tid][1] + wcnt[tid][2] + wcnt[tid][3];
}

// per-offset chunk-count scan (relative) + per-offset raw totals -> segs[k]
__global__ __launch_bounds__(256) void k_segscan(const int* __restrict__ cnt2,
                                                 int* __restrict__ choff,
                                                 int* __restrict__ segs) {
  __shared__ int sc[256];
  int k = blockIdx.x, t = threadIdx.x;
  int v[4];
  #pragma unroll
  for (int i = 0; i < 4; ++i) {
    int idx = t * 4 + i;
    v[i] = (idx < NCH) ? cnt2[k * NCH + idx] : 0;
  }
  int s = v[0] + v[1] + v[2] + v[3];
  sc[t] = s;
  __syncthreads();
  for (int off = 1; off < 256; off <<= 1) {
    int x = (t >= off) ? sc[t - off] : 0;
    __syncthreads();
    sc[t] += x;
    __syncthreads();
  }
  int run = sc[t] - s;
  #pragma unroll
  for (int i = 0; i < 4; ++i) {
    int idx = t * 4 + i;
    if (idx < NCH) choff[k * NCH + idx] = run;
    run += v[i];
  }
  if (t == 255) segs[k] = sc[255];
}

// fused: pair emission (blocks [0, PAIRS_BLKS)) + feats cast + weight packs
__global__ __launch_bounds__(256) void k_pairs_prep(
    int* __restrict__ nbrp, const int* __restrict__ choff,
    const int* __restrict__ segs, int* __restrict__ inl,
    const float* __restrict__ feats, const int* __restrict__ perm,
    const float* __restrict__ w1, const float* __restrict__ w2,
    ushort* __restrict__ fbp, ushort* __restrict__ wp1,
    ushort* __restrict__ wp2) {
  int b = blockIdx.x;
  if (b < PAIRS_BLKS) {
    __shared__ int wsum[4];
    int k = b / NCH, cch = b % NCH;
    // inline padded segment base for offset k
    int base = 0;
    #pragma unroll 1
    for (int kk = 0; kk < K27; ++kk) {
      if (kk == k) break;
      base += (segs[kk] + 63) & ~63;
    }
    int j = cch * 256 + threadIdx.x;
    int v = (j < N_VOX) ? nbrp[k * N_VOX + j] : -1;
    bool valid = v >= 0;
    unsigned long long bal = __ballot(valid);
    int lane = threadIdx.x & 63, wv = threadIdx.x >> 6;
    int before = __popcll(bal & ((1ull << lane) - 1ull));
    if (lane == 0) wsum[wv] = __popcll(bal);
    __syncthreads();
    int woff = 0;
    #pragma unroll
    for (int w = 0; w < 4; ++w) woff += (w < wv) ? wsum[w] : 0;
    if (valid) {
      int p = base + choff[k * NCH + cch] + woff + before;
      inl[p] = v;
      nbrp[k * N_VOX + j] = p;
    }
  } else if (b < PAIRS_BLKS + PREP_FEAT) {
    int i = (b - PAIRS_BLKS) * 256 + threadIdx.x;  // N*16 float4 groups
    int j = i >> 4, seg = i & 15;
    int p = perm[j];
    float4 v = reinterpret_cast<const float4*>(feats)[(p << 4) + seg];
    ushort4 o;
    o.x = f2bf(v.x); o.y = f2bf(v.y); o.z = f2bf(v.z); o.w = f2bf(v.w);
    reinterpret_cast<ushort4*>(fbp)[i] = o;
  } else {
    int b2 = b - PAIRS_BLKS - PREP_FEAT;  // [0, 2*PREP_W)
    const float* w = (b2 < PREP_W) ? w1 : w2;
    ushort* wp = (b2 < PREP_W) ? wp1 : wp2;
    int i = (b2 < PREP_W ? b2 : b2 - PREP_W) * 256 + threadIdx.x;
    int k = i >> 12, r = i & 4095, ci = r >> 6, co = r & 63;
    int ch = co >> 5, row = co & 31;
    int ks = ci >> 4, hi1 = (ci >> 3) & 1, e = ci & 7;
    int dst = ((((k * 2 + ch) * 4 + ks) * 2 + hi1) << 8) + row * 8 + e;
    wp[dst] = f2bf(w[i]);
  }
}

// ---------------- conv phase A: pair GEMM -> pv (LDS-staged stores) --------
template <bool APPLY_BN>
__global__ __launch_bounds__(256, 4) void k_pva(
    const ushort* __restrict__ fin,   // [N][64] bf16 (rank space)
    const ushort* __restrict__ wp,    // packed weight frags
    const int* __restrict__ inl,      // [PAIR_CAP] input ranks (valid region)
    const int* __restrict__ segs,     // [27] raw counts
    const float* __restrict__ ab,     // [128] scale/shift (APPLY_BN)
    ushort* __restrict__ pv) {        // [PAIR_CAP][64]
  __shared__ ushort tile[64 * 64];    // 8 KB, 16B-unit XOR swizzle
  __shared__ float abl[128];
  const int tid = threadIdx.x;
  const int p0 = blockIdx.x * 64;

  // inline tile->k: find padded segment containing p0
  int base = 0, kk = -1, off = 0, cnt = 0;
  #pragma unroll 1
  for (int k = 0; k < K27; ++k) {
    int raw = segs[k];
    int padded = (raw + 63) & ~63;
    if (p0 >= base && p0 < base + padded) { kk = k; off = base; cnt = raw; }
    base += padded;
  }
  if (kk < 0) return;  // beyond total padded pairs

  if (APPLY_BN) {
    if (tid < 128) abl[tid] = ab[tid];
    __syncthreads();
  }

  const int lane = tid & 63, wv = tid >> 6;
  const int lo = lane & 31, hi = lane >> 5;
  const int ch = wv & 1, vh = wv >> 1;
  const int pr = p0 + vh * 32 + lo;
  const bool vld = (pr - off) < cnt;
  const int idx = vld ? inl[pr] : -1;

  const char* wk = (const char*)wp + (kk << 13) + (ch << 12) + (lane << 4);
  short8 a0 = *(const short8*)(wk);
  short8 a1 = *(const short8*)(wk + 1024);
  short8 a2 = *(const short8*)(wk + 2048);
  short8 a3 = *(const short8*)(wk + 3072);

  short8 b0, b1, b2, b3;
  if (idx >= 0) {
    const char* b = (const char*)fin + ((size_t)idx << 7) + (hi << 4);
    b0 = *(const short8*)(b);
    b1 = *(const short8*)(b + 32);
    b2 = *(const short8*)(b + 64);
    b3 = *(const short8*)(b + 96);
    if (APPLY_BN) {
      #pragma unroll
      for (int ks = 0; ks < 4; ++ks) {
        short8& v = ks == 0 ? b0 : ks == 1 ? b1 : ks == 2 ? b2 : b3;
        int cb = ks * 16 + hi * 8;
        #pragma unroll
        for (int e = 0; e < 8; ++e) {
          float x = bf2f((ushort)v[e]);
          x = fmaxf(x * abl[cb + e] + abl[64 + cb + e], 0.f);
          v[e] = (short)f2bf(x);
        }
      }
    }
  } else {
    b0 = short8{0,0,0,0,0,0,0,0}; b1 = b0; b2 = b0; b3 = b0;
  }

  floatx16 acc;
  #pragma unroll
  for (int j = 0; j < 16; ++j) acc[j] = 0.f;
  acc = __builtin_amdgcn_mfma_f32_32x32x16_bf16(a0, b0, acc, 0, 0, 0);
  acc = __builtin_amdgcn_mfma_f32_32x32x16_bf16(a1, b1, acc, 0, 0, 0);
  acc = __builtin_amdgcn_mfma_f32_32x32x16_bf16(a2, b2, acc, 0, 0, 0);
  acc = __builtin_amdgcn_mfma_f32_32x32x16_bf16(a3, b3, acc, 0, 0, 0);

  // stage into LDS: local row r, channel bytes = ch*64 + rg*16 + hi*8 (+r3*2)
  {
    int r = vh * 32 + lo, rx = r & 7;
    char* trow = (char*)tile + r * 128 + hi * 8;
    #pragma unroll
    for (int rg = 0; rg < 4; ++rg) {
      ushort4 v;
      v.x = f2bf(acc[rg * 4 + 0]); v.y = f2bf(acc[rg * 4 + 1]);
      v.z = f2bf(acc[rg * 4 + 2]); v.w = f2bf(acc[rg * 4 + 3]);
      *(ushort4*)(trow + (((ch * 4 + rg) ^ rx) << 4)) = v;
    }
  }
  __syncthreads();
  // coalesced copy: thread copies 32B; row = tid>>2, chunk = tid&3
  {
    int row = tid >> 2, rx = row & 7, chunk = tid & 3;
    const char* src = (const char*)tile + row * 128;
    uint4 x = *(const uint4*)(src + (((chunk * 2) ^ rx) << 4));
    uint4 y = *(const uint4*)(src + (((chunk * 2 + 1) ^ rx) << 4));
    char* dst = (char*)pv + ((size_t)(p0 + row) << 7) + chunk * 32;
    *(uint4*)(dst) = x;
    *(uint4*)(dst + 16) = y;
  }
}

// ---------------- conv phase B: segmented sum + stats ----------------
__global__ __launch_bounds__(256) void k_pvb(
    const ushort* __restrict__ pv,    // [PAIR_CAP][64]
    const int* __restrict__ pidx,     // [27][N] pair ids (-1 invalid)
    ushort* __restrict__ fout,        // [N][64] bf16
    float* __restrict__ part) {       // [PBB][128]
  __shared__ float sred[4][8][16];
  const int tid = threadIdx.x, lane = tid & 63, wv = tid >> 6;
  const int g = tid >> 3, e = tid & 7;
  const int j = blockIdx.x * 32 + g;

  int p[27];
  #pragma unroll
  for (int t = 0; t < K27; ++t) p[t] = pidx[t * N_VOX + j];

  float acc[8];
  #pragma unroll
  for (int r = 0; r < 8; ++r) acc[r] = 0.f;
  #pragma unroll
  for (int t = 0; t < K27; ++t) {
    if (p[t] >= 0) {
      short8 v = *(const short8*)(pv + ((size_t)p[t] << 6) + (e << 3));
      #pragma unroll
      for (int r = 0; r < 8; ++r) acc[r] += bf2f((ushort)v[r]);
    }
  }

  ushort* o = fout + ((size_t)j << 6) + (e << 3);
  ushort4 v0, v1;
  v0.x = f2bf(acc[0]); v0.y = f2bf(acc[1]);
  v0.z = f2bf(acc[2]); v0.w = f2bf(acc[3]);
  v1.x = f2bf(acc[4]); v1.y = f2bf(acc[5]);
  v1.z = f2bf(acc[6]); v1.w = f2bf(acc[7]);
  *(ushort4*)o = v0;
  *(ushort4*)(o + 4) = v1;

  #pragma unroll
  for (int r = 0; r < 8; ++r) {
    float s = acc[r], ss = acc[r] * acc[r];
    s += __shfl_xor(s, 8);  ss += __shfl_xor(ss, 8);
    s += __shfl_xor(s, 16); ss += __shfl_xor(ss, 16);
    s += __shfl_xor(s, 32); ss += __shfl_xor(ss, 32);
    if (lane < 8) { sred[wv][lane][r] = s; sred[wv][lane][8 + r] = ss; }
  }
  __syncthreads();
  if (tid < 128) {
    int half = tid >> 6, chn = tid & 63;
    int e2 = chn >> 3, r2 = chn & 7;
    float v = sred[0][e2][half * 8 + r2] + sred[1][e2][half * 8 + r2] +
              sred[2][e2][half * 8 + r2] + sred[3][e2][half * 8 + r2];
    part[(size_t)blockIdx.x * 128 + tid] = v;
  }
}

// ---------------- BN / epilogue ----------------

__global__ __launch_bounds__(256) void k_red(const float* __restrict__ part,
                                             float* __restrict__ part2) {
  __shared__ float red[256];
  int tid = threadIdx.x;
  int e = tid & 127, g = tid >> 7;
  float s = 0.f;
  for (int r = blockIdx.x * 2 + g; r < PBB; r += 2 * RBLK)
    s += part[(size_t)r * 128 + e];
  red[tid] = s;
  __syncthreads();
  if (tid < 128) part2[(size_t)blockIdx.x * 128 + tid] = red[tid] + red[tid + 128];
}

__global__ __launch_bounds__(256) void k_bnfin(const float* __restrict__ part2,
                                               const float* __restrict__ gamma,
                                               const float* __restrict__ beta,
                                               float* __restrict__ ab) {
  __shared__ float fin[128];
  int tid = threadIdx.x;
  if (tid < 128) {
    float s = 0.f;
    for (int r = 0; r < RBLK; ++r) s += part2[(size_t)r * 128 + tid];
    fin[tid] = s;
  }
  __syncthreads();
  if (tid < 64) {
    float su = fin[tid], ss = fin[64 + tid];
    float mean = su / (float)N_VOX;
    float var  = ss / (float)N_VOX - mean * mean;
    float a = gamma[tid] * rsqrtf(var + EPSF);
    ab[tid]      = a;
    ab[64 + tid] = beta[tid] - mean * a;
  }
}

// BN2 + residual(bf16 fbp) + ReLU; h2p/fbp linear reads, perm-scatter out
__global__ __launch_bounds__(256) void k_final(const ushort* __restrict__ h2p,
                                               const ushort* __restrict__ fbp,
                                               const int* __restrict__ perm,
                                               const float* __restrict__ ab,
                                               float* __restrict__ out) {
  int i = blockIdx.x * 256 + threadIdx.x;  // N*16 quad groups
  int j = i >> 4, seg = i & 15;
  int p = perm[j];
  ushort4 h = reinterpret_cast<const ushort4*>(h2p)[i];
  ushort4 f = reinterpret_cast<const ushort4*>(fbp)[i];
  int cb = seg * 4;
  float4 o;
  o.x = fmaxf(bf2f(h.x) * ab[cb]     + ab[64 + cb]     + bf2f(f.x), 0.f);
  o.y = fmaxf(bf2f(h.y) * ab[cb + 1] + ab[64 + cb + 1] + bf2f(f.y), 0.f);
  o.z = fmaxf(bf2f(h.z) * ab[cb + 2] + ab[64 + cb + 2] + bf2f(f.z), 0.f);
  o.w = fmaxf(bf2f(h.w) * ab[cb + 3] + ab[64 + cb + 3] + bf2f(f.w), 0.f);
  reinterpret_cast<float4*>(out)[(p << 4) + seg] = o;
}

extern "C" void kernel_launch(void* const* d_in, const int* in_sizes, int n_in,
                              void* d_out, int out_size, void* d_ws, size_t ws_size,
                              hipStream_t stream) {
  const float* feats  = (const float*)d_in[0];
  const float* w1     = (const float*)d_in[1];
  const float* g1     = (const float*)d_in[2];
  const float* b1     = (const float*)d_in[3];
  const float* w2     = (const float*)d_in[4];
  const float* g2     = (const float*)d_in[5];
  const float* b2     = (const float*)d_in[6];
  const int*   coords = (const int*)d_in[7];
  float* out = (float*)d_out;

  char* ws = (char*)d_ws;
  ushort* pv    = (ushort*)ws;  ws += (size_t)PAIR_CAP * C * 2;    // 58.9 MB
  int*    table = (int*)ws;     ws += (size_t)TBL_N * 4;           // 16.8 MB
  int*    nbrp  = (int*)ws;     ws += (size_t)K27 * N_VOX * 4;     // 21.6 MB
  ushort* fbp   = (ushort*)ws;  ws += (size_t)N_VOX * C * 2;       // 25.6 MB
  ushort* h1p   = (ushort*)ws;  ws += (size_t)N_VOX * C * 2;       // 25.6 MB
  ushort* h2p   = (ushort*)ws;  ws += (size_t)N_VOX * C * 2;       // 25.6 MB
  int*    perm  = (int*)ws;     ws += (size_t)N_VOX * 4;
  ushort* wp1   = (ushort*)ws;  ws += (size_t)K27 * 4096 * 2;
  ushort* wp2   = (ushort*)ws;  ws += (size_t)K27 * 4096 * 2;
  int*    inl   = (int*)ws;     ws += (size_t)PAIR_CAP * 4;
  int*    bsum  = (int*)ws;     ws += 4096 * 4;
  int*    boff  = (int*)ws;     ws += 4096 * 4;
  int*    cnt2  = (int*)ws;     ws += (size_t)K27 * NCH * 4;
  int*    choff = (int*)ws;     ws += (size_t)K27 * NCH * 4;
  int*    segs  = (int*)ws;     ws += 256;
  float*  part2 = (float*)ws;   ws += (size_t)RBLK * 128 * 4;
  float*  ab1   = (float*)ws;   ws += 512;
  float*  ab2   = (float*)ws;   ws += 512;
  float*  part  = (float*)table;   // alias: table dead after k_nbrc

  // rulebook
  k_fill<<<TBL_N / 256, 256, 0, stream>>>(table, bsum);
  k_scatcnt<<<(N_VOX + 255) / 256, 256, 0, stream>>>(coords, table, bsum);
  k_scan<<<1, 1024, 0, stream>>>(bsum, boff);
  k_compact<<<TBL_N / 1024, 1024, 0, stream>>>(table, boff, perm);
  k_nbrc<<<NCH, 256, 0, stream>>>(coords, table, perm, nbrp, cnt2);
  k_segscan<<<K27, 256, 0, stream>>>(cnt2, choff, segs);
  k_pairs_prep<<<PAIRS_BLKS + PREP_FEAT + 2 * PREP_W, 256, 0, stream>>>(
      nbrp, choff, segs, inl, feats, perm, w1, w2, fbp, wp1, wp2);

  // conv1 (raw conv output -> h1p bf16; stats fused)
  k_pva<false><<<TIL64, 256, 0, stream>>>(fbp, wp1, inl, segs, ab1, pv);
  k_pvb<<<PBB, 256, 0, stream>>>(pv, nbrp, h1p, part);
  k_red<<<RBLK, 256, 0, stream>>>(part, part2);
  k_bnfin<<<1, 256, 0, stream>>>(part2, g1, b1, ab1);

  // conv2 (BN1+ReLU applied during gather; raw conv2 -> h2p bf16)
  k_pva<true><<<TIL64, 256, 0, stream>>>(h1p, wp2, inl, segs, ab1, pv);
  k_pvb<<<PBB, 256, 0, stream>>>(pv, nbrp, h2p, part);
  k_red<<<RBLK, 256, 0, stream>>>(part, part2);
  k_bnfin<<<1, 256, 0, stream>>>(part2, g2, b2, ab2);

  // BN2 + residual + ReLU -> d_out (original order)
  k_final<<<N_VOX * 16 / 256, 256, 0, stream>>>(h2p, fbp, perm, ab2, out);
}